// Round 11
// baseline (617.412 us; speedup 1.0000x reference)
//
#include <hip/hip_runtime.h>
#include <hip/hip_bf16.h>
#include <hip/hip_fp16.h>

// Problem constants (from reference setup_inputs)
constexpr int NN   = 50000;   // nodes
constexpr int EE   = 400000;  // edges (before self loops)
constexpr int EP   = 450000;  // edges + self loops
constexpr int D    = 512;     // HEADS*CH
constexpr int D2   = 1024;    // XL||XR fused row stride
constexpr int F0   = 55;      // input feature dim
constexpr int F0P  = 64;      // padded to MFMA K granularity
constexpr int OUTC = 49;      // classifier out dim

typedef _Float16 f16;
typedef _Float16 h2 __attribute__((ext_vector_type(2)));

using frag_ab = __attribute__((ext_vector_type(8))) _Float16; // 8 f16 (4 VGPRs)
using frag_cd = __attribute__((ext_vector_type(4))) float;    // 4 fp32

__device__ inline void stf(float* p, float v) { *p = v; }
__device__ inline void stf(f16* p, float v)   { *p = (f16)v; }

// ---------------------------------------------------------------------------
// MFMA f16 GEMM (round-7 known-good structure, dtype bf16->f16): C = A @ B,
// B TRANSPOSED as Bt[*,K]. 128x128 tile, BK=32, 256 thr, 4 waves x 4x4 frags.
// Ncs = C row stride AND column bound. K % 32 == 0. gridDim.x==8 -> XCD swizzle
// (keeps a row-slab's 8 column tiles on ONE XCD: A slab L2-resident, FETCH
// 202->35 MB verified round 7). Do NOT re-attempt LDS swizzle/BK=64 (round-8
// regression: conflicts were 0.01% of cycles; occupancy loss dominated).
// ---------------------------------------------------------------------------
template <typename TC>
__global__ __launch_bounds__(256) void gemm_mfma_bt(
    const f16* __restrict__ A,    // [M,K]
    const f16* __restrict__ Bt,   // [gridx*128, K]
    TC* __restrict__ C,           // [M, Ncs]
    const float* __restrict__ bias,
    int M, int Ncs, int K)
{
    constexpr int BM = 128, BN = 128, BK = 32;
    __shared__ f16 As[BM * BK];   // row-major, stride BK (64 B/row)
    __shared__ f16 Bs[BN * BK];

    int bx = blockIdx.x, by = blockIdx.y;
    if (gridDim.x == 8) {
        int bid = by * 8 + bx;
        bx = (bid >> 3) & 7;
        by = (bid & 7) + ((bid >> 6) << 3);
        if (by * BM >= M) return;   // uniform across block
    }

    const int tid  = threadIdx.x;
    const int wave = tid >> 6;
    const int lane = tid & 63;
    const int rowBase = by * BM;
    const int colBase = bx * BN;

    frag_cd acc[4][4] = {};

    int arow0 = rowBase + wave * 32 + (lane >> 2);
    int arow1 = arow0 + 16;
    if (arow0 >= M) arow0 = M - 1;   // clamp: garbage rows never stored
    if (arow1 >= M) arow1 = M - 1;
    const f16* gA0 = A + (size_t)arow0 * K + (lane & 3) * 8;
    const f16* gA1 = A + (size_t)arow1 * K + (lane & 3) * 8;
    const int brow0 = colBase + wave * 32 + (lane >> 2);
    const f16* gB0 = Bt + (size_t)brow0 * K + (lane & 3) * 8;
    const f16* gB1 = gB0 + (size_t)16 * K;

    f16* lA0 = &As[(wave * 32)      * BK];
    f16* lA1 = &As[(wave * 32 + 16) * BK];
    f16* lB0 = &Bs[(wave * 32)      * BK];
    f16* lB1 = &Bs[(wave * 32 + 16) * BK];

    const int m  = lane & 15;
    const int kq = lane >> 4;
    const int wm = (wave >> 1) * 64;
    const int wn = (wave & 1) * 64;

    for (int k0 = 0; k0 < K; k0 += BK) {
        __builtin_amdgcn_global_load_lds(
            (const __attribute__((address_space(1))) void*)(gA0 + k0),
            (__attribute__((address_space(3))) void*)lA0, 16, 0, 0);
        __builtin_amdgcn_global_load_lds(
            (const __attribute__((address_space(1))) void*)(gA1 + k0),
            (__attribute__((address_space(3))) void*)lA1, 16, 0, 0);
        __builtin_amdgcn_global_load_lds(
            (const __attribute__((address_space(1))) void*)(gB0 + k0),
            (__attribute__((address_space(3))) void*)lB0, 16, 0, 0);
        __builtin_amdgcn_global_load_lds(
            (const __attribute__((address_space(1))) void*)(gB1 + k0),
            (__attribute__((address_space(3))) void*)lB1, 16, 0, 0);
        __syncthreads();

        frag_ab a[4], b[4];
        #pragma unroll
        for (int i = 0; i < 4; ++i)
            a[i] = *(const frag_ab*)&As[(wm + i * 16 + m) * BK + kq * 8];
        #pragma unroll
        for (int j = 0; j < 4; ++j)
            b[j] = *(const frag_ab*)&Bs[(wn + j * 16 + m) * BK + kq * 8];
        #pragma unroll
        for (int i = 0; i < 4; ++i)
            #pragma unroll
            for (int j = 0; j < 4; ++j)
                acc[i][j] = __builtin_amdgcn_mfma_f32_16x16x32_f16(
                    a[i], b[j], acc[i][j], 0, 0, 0);
        __syncthreads();
    }

    // epilogue: C/D layout col=lane&15, row=(lane>>4)*4+reg (shape-determined,
    // dtype-independent — m89/m101/m121 verified)
    #pragma unroll
    for (int i = 0; i < 4; ++i) {
        #pragma unroll
        for (int r = 0; r < 4; ++r) {
            int row = rowBase + wm + i * 16 + kq * 4 + r;
            if (row >= M) continue;
            #pragma unroll
            for (int j = 0; j < 4; ++j) {
                int col = colBase + wn + j * 16 + m;
                if (col >= Ncs) continue;
                float v = acc[i][j][r];
                if (bias) v += bias[col];
                stf(&C[(size_t)row * Ncs + col], v);
            }
        }
    }
}

// ---------------------------------------------------------------------------
// weight prep kernels (fp32 -> f16)
// ---------------------------------------------------------------------------
__global__ void convert_transpose(const float* __restrict__ W, f16* __restrict__ Wt,
                                  int K, int N) {
    __shared__ float tile[32][33];
    int bn = blockIdx.x * 32, bk = blockIdx.y * 32;
    int tx = threadIdx.x & 31, ty = threadIdx.x >> 5;  // 32x8
    #pragma unroll
    for (int i = 0; i < 32; i += 8)
        tile[ty + i][tx] = W[(size_t)(bk + ty + i) * N + bn + tx];
    __syncthreads();
    #pragma unroll
    for (int i = 0; i < 32; i += 8)
        Wt[(size_t)(bn + ty + i) * K + bk + tx] = (f16)tile[tx][ty + i];
}

__global__ void pad_convert_x(const float* __restrict__ x, f16* __restrict__ Xp) {
    int idx = blockIdx.x * blockDim.x + threadIdx.x;
    if (idx >= NN * F0P) return;
    int n = idx >> 6, t = idx & 63;
    float v = (t < F0) ? x[n * F0 + t] : 0.f;
    Xp[idx] = (f16)v;
}

__global__ void conv_transpose_w1(const float* __restrict__ W, f16* __restrict__ Wt) {
    int n = blockIdx.x;           // 512
    int k = threadIdx.x;          // 64
    float v = (k < F0) ? W[(size_t)k * D + n] : 0.f;
    Wt[n * F0P + k] = (f16)v;
}

__global__ void conv_transpose_wc(const float* __restrict__ W, f16* __restrict__ Wt) {
    int n = blockIdx.x;           // 128
    for (int k = threadIdx.x; k < D; k += blockDim.x) {
        float v = (n < OUTC) ? W[(size_t)k * OUTC + n] : 0.f;
        Wt[(size_t)n * D + k] = (f16)v;
    }
}

// ---------------------------------------------------------------------------
__global__ void zero_ints(int* __restrict__ p, int n) {
    int i = blockIdx.x * blockDim.x + threadIdx.x;
    if (i < n) p[i] = 0;
}

// ---------------------------------------------------------------------------
// CSR build by destination; srcPos[pos] = source node of CSR slot pos
// ---------------------------------------------------------------------------
__global__ void count_dst(const int* __restrict__ dstIdx, int* __restrict__ cnt) {
    int e = blockIdx.x * blockDim.x + threadIdx.x;
    if (e >= EP) return;
    int dst = (e < EE) ? dstIdx[e] : (e - EE);
    atomicAdd(&cnt[dst], 1);
}

__global__ void scan_blocks(const int* __restrict__ cnt, int* __restrict__ off,
                            int* __restrict__ bsum) {
    __shared__ int sh[1024];
    int i = blockIdx.x * 1024 + threadIdx.x;
    int v = (i < NN) ? cnt[i] : 0;
    sh[threadIdx.x] = v;
    __syncthreads();
    #pragma unroll
    for (int d = 1; d < 1024; d <<= 1) {
        int t = (threadIdx.x >= d) ? sh[threadIdx.x - d] : 0;
        __syncthreads();
        sh[threadIdx.x] += t;
        __syncthreads();
    }
    if (i < NN) off[i] = sh[threadIdx.x] - v;   // local exclusive
    if (threadIdx.x == 1023) bsum[blockIdx.x] = sh[1023];
}

__global__ void scan_bsums(int* __restrict__ bsum, int* __restrict__ bbase,
                           int* __restrict__ off, int nb) {
    int lane = threadIdx.x;  // single wave of 64
    int orig = (lane < nb) ? bsum[lane] : 0;
    int v = orig;
    #pragma unroll
    for (int d = 1; d < 64; d <<= 1) {
        int t = __shfl_up(v, d);
        if (lane >= d) v += t;
    }
    if (lane < nb) bbase[lane] = v - orig;      // exclusive base per block
    if (lane == 63) off[NN] = v;                // grand total
}

__global__ void add_base(int* __restrict__ off, const int* __restrict__ bbase) {
    int i = blockIdx.x * 1024 + threadIdx.x;
    if (blockIdx.x == 0 || i >= NN) return;
    off[i] += bbase[blockIdx.x];
}

__global__ void fill_srcpos(const int* __restrict__ srcIdx, const int* __restrict__ dstIdx,
                            const int* __restrict__ off, int* __restrict__ cnt,
                            int* __restrict__ srcPos) {
    int e = blockIdx.x * blockDim.x + threadIdx.x;
    if (e >= EP) return;
    int dst = (e < EE) ? dstIdx[e] : (e - EE);
    int src = (e < EE) ? srcIdx[e] : (e - EE);
    int pos = off[dst] + atomicAdd(&cnt[dst], 1);
    srcPos[pos] = src;
}

// ---------------------------------------------------------------------------
// FUSED per-node GATv2 edge phase. ONE wave per destination node (round-9
// showed VALU-bound, not latency — keep 1 wave/node, depth-2 prefetch).
// fp16 packed math: logit pipeline = 4x v_pk_add_f16 + 4x v_pk_mul_f16 +
// 4x v_pk_max_f16 + 4x v_dot2_f32_f16 (vs ~40 scalar fp32 ops in bf16 path).
// Softmax uses CLAMPED exp (shift-free, round-10 verified). Lane l owns
// channels [l*8, l*8+8); head = l>>4. XLR: [XL(512)|XR(512)] f16, stride D2.
// ---------------------------------------------------------------------------
__global__ __launch_bounds__(256) void gat_edge_fused(
    const f16* __restrict__ XLR, const float* __restrict__ att,
    const int* __restrict__ off, const int* __restrict__ srcPos,
    const float* __restrict__ bias, f16* __restrict__ Hout)
{
    int v = blockIdx.x * 4 + (threadIdx.x >> 6);
    if (v >= NN) return;
    int lane = threadIdx.x & 63;

    h2 xr[4];
    { uint4 t = *(const uint4*)(XLR + (size_t)v * D2 + D + lane * 8);
      __builtin_memcpy(xr, &t, 16); }
    const float4* a4 = (const float4*)(att + lane * 8);
    float4 aa = a4[0], ab = a4[1];
    h2 at[4] = { h2{(f16)aa.x, (f16)aa.y}, h2{(f16)aa.z, (f16)aa.w},
                 h2{(f16)ab.x, (f16)ab.y}, h2{(f16)ab.z, (f16)ab.w} };
    const h2 c02 = h2{(f16)0.2f, (f16)0.2f};

    int s0 = off[v], s1 = off[v + 1];
    float den = 0.f;
    float acc[8] = {};

    uint4 lb0 = {0, 0, 0, 0}, lb1 = {0, 0, 0, 0};
    if (s0 < s1)     lb0 = *(const uint4*)(XLR + (size_t)srcPos[s0] * D2 + lane * 8);
    if (s0 + 1 < s1) lb1 = *(const uint4*)(XLR + (size_t)srcPos[s0 + 1] * D2 + lane * 8);

    for (int i = s0; i < s1; ++i) {
        uint4 cur = lb0;
        lb0 = lb1;
        if (i + 2 < s1)
            lb1 = *(const uint4*)(XLR + (size_t)srcPos[i + 2] * D2 + lane * 8);

        h2 xl[4];
        __builtin_memcpy(xl, &cur, 16);
        float s = 0.f;
        #pragma unroll
        for (int j = 0; j < 4; ++j) {
            h2 t  = xl[j] + xr[j];                       // v_pk_add_f16
            h2 lt = __builtin_elementwise_max(t, t * c02); // pk_mul + pk_max
            s = __builtin_amdgcn_fdot2(lt, at[j], s, false); // v_dot2_f32_f16
        }
        s += __shfl_xor(s, 1);
        s += __shfl_xor(s, 2);
        s += __shfl_xor(s, 4);
        s += __shfl_xor(s, 8);               // 16 lanes of head hold logit
        s = fminf(fmaxf(s, -60.f), 60.f);    // shift-free softmax, clamped
        float p = __expf(s);
        den += p;
        #pragma unroll
        for (int j = 0; j < 4; ++j) {        // v_fma_mix-able: f16 src, f32 acc
            acc[2 * j]     = fmaf(p, (float)xl[j].x, acc[2 * j]);
            acc[2 * j + 1] = fmaf(p, (float)xl[j].y, acc[2 * j + 1]);
        }
    }
    float r = 1.f / den;

    const float4* b4 = (const float4*)(bias + lane * 8);
    float4 ba = b4[0], bb = b4[1];
    float bi[8] = {ba.x, ba.y, ba.z, ba.w, bb.x, bb.y, bb.z, bb.w};
    h2 ov[4];
    #pragma unroll
    for (int j = 0; j < 4; ++j) {
        float o0 = acc[2 * j] * r + bi[2 * j];
        float o1 = acc[2 * j + 1] * r + bi[2 * j + 1];
        o0 = o0 > 0.f ? o0 : (__expf(o0) - 1.f);   // ELU
        o1 = o1 > 0.f ? o1 : (__expf(o1) - 1.f);
        ov[j] = h2{(f16)o0, (f16)o1};
    }
    uint4 ou;
    __builtin_memcpy(&ou, ov, 16);
    *(uint4*)(Hout + (size_t)v * D + lane * 8) = ou;
}

// ---------------------------------------------------------------------------
extern "C" void kernel_launch(void* const* d_in, const int* in_sizes, int n_in,
                              void* d_out, int out_size, void* d_ws, size_t ws_size,
                              hipStream_t stream) {
    const float* x    = (const float*)d_in[0];
    const int*   ei   = (const int*)d_in[1];
    const float* W1l  = (const float*)d_in[2];
    const float* W1r  = (const float*)d_in[3];
    const float* att1 = (const float*)d_in[4];
    const float* b1   = (const float*)d_in[5];
    const float* W2l  = (const float*)d_in[6];
    const float* W2r  = (const float*)d_in[7];
    const float* att2 = (const float*)d_in[8];
    const float* b2   = (const float*)d_in[9];
    const float* Wc   = (const float*)d_in[10];
    const float* bc   = (const float*)d_in[11];
    float* out = (float*)d_out;

    const int* srcIdx = ei;
    const int* dstIdx = ei + EE;

    constexpr int NB = (NN + 1023) / 1024;   // 49 scan blocks

    // workspace carve — total ≈ 166 MB
    f16* XLR  = (f16*)d_ws;                     // NN*D2   (XL || XR)
    f16* Hb   = XLR + (size_t)NN * D2;          // NN*D
    f16* Xpad = Hb + (size_t)NN * D;            // NN*F0P
    f16* W2T  = Xpad + (size_t)NN * F0P;        // 1024*D   (W2lT || W2rT rows)
    f16* W1T  = W2T + (size_t)D2 * D;           // 1024*F0P
    f16* WcT  = W1T + (size_t)D2 * F0P;         // 128*D
    int* cnt   = (int*)(WcT + (size_t)128 * D); // NN
    int* cnt2  = cnt + NN;                      // NN
    int* off   = cnt2 + NN;                     // NN+1
    int* srcPos= off + (NN + 1);                // EP
    int* bsum  = srcPos + EP;                   // NB
    int* bbase = bsum + NB;                     // NB

    // ---- one-time per call: CSR build + weight prep ----
    zero_ints<<<(2 * NN + 255) / 256, 256, 0, stream>>>(cnt, 2 * NN);
    count_dst<<<(EP + 255) / 256, 256, 0, stream>>>(dstIdx, cnt);
    scan_blocks<<<NB, 1024, 0, stream>>>(cnt, off, bsum);
    scan_bsums<<<1, 64, 0, stream>>>(bsum, bbase, off, NB);
    add_base<<<NB, 1024, 0, stream>>>(off, bbase);
    fill_srcpos<<<(EP + 255) / 256, 256, 0, stream>>>(srcIdx, dstIdx, off, cnt2, srcPos);

    dim3 ctGrid(D / 32, D / 32);
    convert_transpose<<<ctGrid, 256, 0, stream>>>(W2l, W2T, D, D);                 // rows 0..511
    convert_transpose<<<ctGrid, 256, 0, stream>>>(W2r, W2T + (size_t)D * D, D, D); // rows 512..1023
    conv_transpose_w1<<<D, F0P, 0, stream>>>(W1l, W1T);
    conv_transpose_w1<<<D, F0P, 0, stream>>>(W1r, W1T + (size_t)D * F0P);
    conv_transpose_wc<<<128, 256, 0, stream>>>(Wc, WcT);
    pad_convert_x<<<(NN * F0P + 255) / 256, 256, 0, stream>>>(x, Xpad);

    // fused L+R GEMM: N=1024, grid.y padded so the XCD swizzle covers all slabs
    dim3 gemmGrid(D2 / 128, ((NN + 127) / 128 + 7) / 8 * 8 + 8);  // 8 x 400
    int nodeBlocks = (NN + 3) / 4;

    // ---- layer 1 (Xpad f16, K=64): one GEMM produces XL||XR ----
    gemm_mfma_bt<f16><<<gemmGrid, 256, 0, stream>>>(Xpad, W1T, XLR, nullptr, NN, D2, F0P);
    gat_edge_fused<<<nodeBlocks, 256, 0, stream>>>(XLR, att1, off, srcPos, b1, Hb);

    // ---- layers 2 & 3 (f16 Hb, K=512; conv2 applied twice) ----
    for (int rep = 0; rep < 2; ++rep) {
        gemm_mfma_bt<f16><<<gemmGrid, 256, 0, stream>>>(Hb, W2T, XLR, nullptr, NN, D2, D);
        gat_edge_fused<<<nodeBlocks, 256, 0, stream>>>(XLR, att2, off, srcPos, b2, Hb);
    }

    // ---- classifier: C[NN,49] fp32 = Hb @ Wc + bc (N padded to 128) ----
    dim3 gridc(1, (NN + 127) / 128);
    gemm_mfma_bt<float><<<gridc, 256, 0, stream>>>(Hb, WcT, out, bc, NN, OUTC, D);
}

// Round 12
// 610.928 us; speedup vs baseline: 1.0106x; 1.0106x over previous
//
#include <hip/hip_runtime.h>
#include <hip/hip_bf16.h>

// Problem constants (from reference setup_inputs)
constexpr int NN   = 50000;   // nodes
constexpr int EE   = 400000;  // edges (before self loops)
constexpr int EP   = 450000;  // edges + self loops
constexpr int D    = 512;     // HEADS*CH
constexpr int D2   = 1024;    // XL||XR fused row stride
constexpr int F0   = 55;      // input feature dim
constexpr int F0P  = 64;      // padded to MFMA K granularity
constexpr int OUTC = 49;      // classifier out dim

typedef __hip_bfloat16 bf16;

using frag_ab  = __attribute__((ext_vector_type(8))) short;   // 8 bf16 (4 VGPRs)
using frag_cd16 = __attribute__((ext_vector_type(16))) float; // 16 fp32 (32x32 acc)

__device__ inline void stf(float* p, float v) { *p = v; }
__device__ inline void stf(bf16* p, float v)  { *p = __float2bfloat16(v); }

// unpack 8 bf16 (packed in a uint4) to 8 floats
__device__ inline void unpack8(uint4 u, float* f) {
    unsigned w[4] = {u.x, u.y, u.z, u.w};
    #pragma unroll
    for (int j = 0; j < 4; ++j) {
        __hip_bfloat162 h = *(__hip_bfloat162*)&w[j];
        float2 t = __bfloat1622float2(h);
        f[2 * j] = t.x; f[2 * j + 1] = t.y;
    }
}

// ---------------------------------------------------------------------------
// MFMA bf16 GEMM: C[M,*] = A @ B, B TRANSPOSED as Bt[*,K].
// Round-7 staging/tile structure (known-good) but inner compute uses
// 2x2 frags of v_mfma_f32_32x32x16_bf16 (8 MFMA/iter vs 16): the 32x32 pipe
// is ~13% more cycle-efficient (m119: 2495 vs 2176 TF) and halves MFMA issue.
// 128x128 tile, BK=32, 256 thr. Ncs = C row stride AND column bound.
// K % 32 == 0. gridDim.x==8 -> XCD swizzle (A slab L2-resident; FETCH
// 202->35 MB verified round 7). Do NOT re-attempt LDS swizzle/BK=64 (r8
// regression: conflicts were 0.01% of cycles; occupancy loss dominated).
// ---------------------------------------------------------------------------
template <typename TC>
__global__ __launch_bounds__(256) void gemm_mfma_bt(
    const bf16* __restrict__ A,   // [M,K]
    const bf16* __restrict__ Bt,  // [gridx*128, K]
    TC* __restrict__ C,           // [M, Ncs]
    const float* __restrict__ bias,
    int M, int Ncs, int K)
{
    constexpr int BM = 128, BN = 128, BK = 32;
    __shared__ bf16 As[BM * BK];  // row-major, stride BK (64 B/row)
    __shared__ bf16 Bs[BN * BK];

    int bx = blockIdx.x, by = blockIdx.y;
    if (gridDim.x == 8) {
        int bid = by * 8 + bx;
        bx = (bid >> 3) & 7;
        by = (bid & 7) + ((bid >> 6) << 3);
        if (by * BM >= M) return;   // uniform across block
    }

    const int tid  = threadIdx.x;
    const int wave = tid >> 6;
    const int lane = tid & 63;
    const int rowBase = by * BM;
    const int colBase = bx * BN;

    frag_cd16 acc[2][2] = {};

    int arow0 = rowBase + wave * 32 + (lane >> 2);
    int arow1 = arow0 + 16;
    if (arow0 >= M) arow0 = M - 1;   // clamp: garbage rows never stored
    if (arow1 >= M) arow1 = M - 1;
    const bf16* gA0 = A + (size_t)arow0 * K + (lane & 3) * 8;
    const bf16* gA1 = A + (size_t)arow1 * K + (lane & 3) * 8;
    const int brow0 = colBase + wave * 32 + (lane >> 2);
    const bf16* gB0 = Bt + (size_t)brow0 * K + (lane & 3) * 8;
    const bf16* gB1 = gB0 + (size_t)16 * K;

    bf16* lA0 = &As[(wave * 32)      * BK];
    bf16* lA1 = &As[(wave * 32 + 16) * BK];
    bf16* lB0 = &Bs[(wave * 32)      * BK];
    bf16* lB1 = &Bs[(wave * 32 + 16) * BK];

    const int m32 = lane & 31;      // row (A) / col (B) within 32
    const int kh  = lane >> 5;      // k-half: k offset = kh*8
    const int wm = (wave >> 1) * 64;
    const int wn = (wave & 1) * 64;

    for (int k0 = 0; k0 < K; k0 += BK) {
        __builtin_amdgcn_global_load_lds(
            (const __attribute__((address_space(1))) void*)(gA0 + k0),
            (__attribute__((address_space(3))) void*)lA0, 16, 0, 0);
        __builtin_amdgcn_global_load_lds(
            (const __attribute__((address_space(1))) void*)(gA1 + k0),
            (__attribute__((address_space(3))) void*)lA1, 16, 0, 0);
        __builtin_amdgcn_global_load_lds(
            (const __attribute__((address_space(1))) void*)(gB0 + k0),
            (__attribute__((address_space(3))) void*)lB0, 16, 0, 0);
        __builtin_amdgcn_global_load_lds(
            (const __attribute__((address_space(1))) void*)(gB1 + k0),
            (__attribute__((address_space(3))) void*)lB1, 16, 0, 0);
        __syncthreads();

        #pragma unroll
        for (int kk = 0; kk < 2; ++kk) {     // two K=16 steps per BK=32
            const int koff = kk * 16 + kh * 8;
            frag_ab a[2], b[2];
            #pragma unroll
            for (int i = 0; i < 2; ++i)
                a[i] = *(const frag_ab*)&As[(wm + i * 32 + m32) * BK + koff];
            #pragma unroll
            for (int j = 0; j < 2; ++j)
                b[j] = *(const frag_ab*)&Bs[(wn + j * 32 + m32) * BK + koff];
            #pragma unroll
            for (int i = 0; i < 2; ++i)
                #pragma unroll
                for (int j = 0; j < 2; ++j)
                    acc[i][j] = __builtin_amdgcn_mfma_f32_32x32x16_bf16(
                        a[i], b[j], acc[i][j], 0, 0, 0);
        }
        __syncthreads();
    }

    // epilogue: 32x32 C/D layout col=lane&31, row=(reg&3)+8*(reg>>2)+4*(lane>>5)
    // [m74/m101 verified; dtype-independent]
    #pragma unroll
    for (int i = 0; i < 2; ++i) {
        #pragma unroll
        for (int r = 0; r < 16; ++r) {
            int row = rowBase + wm + i * 32 + (r & 3) + 8 * (r >> 2) + 4 * kh;
            if (row >= M) continue;
            #pragma unroll
            for (int j = 0; j < 2; ++j) {
                int col = colBase + wn + j * 32 + m32;
                if (col >= Ncs) continue;
                float v = acc[i][j][r];
                if (bias) v += bias[col];
                stf(&C[(size_t)row * Ncs + col], v);
            }
        }
    }
}

// ---------------------------------------------------------------------------
// weight prep kernels
// ---------------------------------------------------------------------------
// fp32 W[512,512] x2 -> bf16 Wt[1024,512] (transposed, stacked), grid.z=2
__global__ void convert_transpose2(const float* __restrict__ W0,
                                   const float* __restrict__ W1,
                                   bf16* __restrict__ Wt) {
    __shared__ float tile[32][33];
    const float* W = blockIdx.z ? W1 : W0;
    bf16* dst = Wt + (size_t)blockIdx.z * D * D;
    int bn = blockIdx.x * 32, bk = blockIdx.y * 32;
    int tx = threadIdx.x & 31, ty = threadIdx.x >> 5;  // 32x8
    #pragma unroll
    for (int i = 0; i < 32; i += 8)
        tile[ty + i][tx] = W[(size_t)(bk + ty + i) * D + bn + tx];
    __syncthreads();
    #pragma unroll
    for (int i = 0; i < 32; i += 8)
        dst[(size_t)(bn + ty + i) * D + bk + tx] = __float2bfloat16(tile[tx][ty + i]);
}

__global__ void pad_convert_x(const float* __restrict__ x, bf16* __restrict__ Xp) {
    int idx = blockIdx.x * blockDim.x + threadIdx.x;
    if (idx >= NN * F0P) return;
    int n = idx >> 6, t = idx & 63;
    float v = (t < F0) ? x[n * F0 + t] : 0.f;
    Xp[idx] = __float2bfloat16(v);
}

// W1{l,r}[55,512] fp32 -> W1T[1024,64] bf16 (zero pad K), grid.y=2
__global__ void conv_transpose_w1(const float* __restrict__ Wl,
                                  const float* __restrict__ Wr,
                                  bf16* __restrict__ Wt) {
    const float* W = blockIdx.y ? Wr : Wl;
    bf16* dst = Wt + (size_t)blockIdx.y * D * F0P;
    int n = blockIdx.x;           // 512
    int k = threadIdx.x;          // 64
    float v = (k < F0) ? W[(size_t)k * D + n] : 0.f;
    dst[n * F0P + k] = __float2bfloat16(v);
}

__global__ void conv_transpose_wc(const float* __restrict__ W, bf16* __restrict__ Wt) {
    int n = blockIdx.x;           // 128
    for (int k = threadIdx.x; k < D; k += blockDim.x) {
        float v = (n < OUTC) ? W[(size_t)k * OUTC + n] : 0.f;
        Wt[(size_t)n * D + k] = __float2bfloat16(v);
    }
}

// ---------------------------------------------------------------------------
__global__ void zero_ints(int* __restrict__ p, int n) {
    int i = blockIdx.x * blockDim.x + threadIdx.x;
    if (i < n) p[i] = 0;
}

// ---------------------------------------------------------------------------
// CSR build by destination; srcPos[pos] = source node of CSR slot pos
// ---------------------------------------------------------------------------
__global__ void count_dst(const int* __restrict__ dstIdx, int* __restrict__ cnt) {
    int e = blockIdx.x * blockDim.x + threadIdx.x;
    if (e >= EP) return;
    int dst = (e < EE) ? dstIdx[e] : (e - EE);
    atomicAdd(&cnt[dst], 1);
}

__global__ void scan_blocks(const int* __restrict__ cnt, int* __restrict__ off,
                            int* __restrict__ bsum) {
    __shared__ int sh[1024];
    int i = blockIdx.x * 1024 + threadIdx.x;
    int v = (i < NN) ? cnt[i] : 0;
    sh[threadIdx.x] = v;
    __syncthreads();
    #pragma unroll
    for (int d = 1; d < 1024; d <<= 1) {
        int t = (threadIdx.x >= d) ? sh[threadIdx.x - d] : 0;
        __syncthreads();
        sh[threadIdx.x] += t;
        __syncthreads();
    }
    if (i < NN) off[i] = sh[threadIdx.x] - v;   // local exclusive
    if (threadIdx.x == 1023) bsum[blockIdx.x] = sh[1023];
}

__global__ void scan_bsums(int* __restrict__ bsum, int* __restrict__ bbase,
                           int* __restrict__ off, int nb) {
    int lane = threadIdx.x;  // single wave of 64
    int orig = (lane < nb) ? bsum[lane] : 0;
    int v = orig;
    #pragma unroll
    for (int d = 1; d < 64; d <<= 1) {
        int t = __shfl_up(v, d);
        if (lane >= d) v += t;
    }
    if (lane < nb) bbase[lane] = v - orig;      // exclusive base per block
    if (lane == 63) off[NN] = v;                // grand total
}

__global__ void add_base(int* __restrict__ off, const int* __restrict__ bbase) {
    int i = blockIdx.x * 1024 + threadIdx.x;
    if (blockIdx.x == 0 || i >= NN) return;
    off[i] += bbase[blockIdx.x];
}

__global__ void fill_srcpos(const int* __restrict__ srcIdx, const int* __restrict__ dstIdx,
                            const int* __restrict__ off, int* __restrict__ cnt,
                            int* __restrict__ srcPos) {
    int e = blockIdx.x * blockDim.x + threadIdx.x;
    if (e >= EP) return;
    int dst = (e < EE) ? dstIdx[e] : (e - EE);
    int src = (e < EE) ? srcIdx[e] : (e - EE);
    int pos = off[dst] + atomicAdd(&cnt[dst], 1);
    srcPos[pos] = src;
}

// ---------------------------------------------------------------------------
// FUSED per-node GATv2 edge phase — round-10 exact version (measured best).
// ONE wave per destination node, depth-2 prefetch, clamped-exp softmax.
// Lane l owns channels [l*8, l*8+8); head = l>>4.
// XLR row layout: [XL(512) | XR(512)] bf16, stride D2. Output Hb + bias + ELU.
// ---------------------------------------------------------------------------
__global__ __launch_bounds__(256) void gat_edge_fused(
    const bf16* __restrict__ XLR, const float* __restrict__ att,
    const int* __restrict__ off, const int* __restrict__ srcPos,
    const float* __restrict__ bias, bf16* __restrict__ Hout)
{
    int v = blockIdx.x * 4 + (threadIdx.x >> 6);
    if (v >= NN) return;
    int lane = threadIdx.x & 63;

    uint4 ru = *(const uint4*)(XLR + (size_t)v * D2 + D + lane * 8);
    float xr[8]; unpack8(ru, xr);
    const float4* a4 = (const float4*)(att + lane * 8);
    float4 aa = a4[0], ab = a4[1];
    float at[8] = {aa.x, aa.y, aa.z, aa.w, ab.x, ab.y, ab.z, ab.w};

    int s0 = off[v], s1 = off[v + 1];
    float den = 0.f;
    float acc[8] = {};

    uint4 lb0 = {0, 0, 0, 0}, lb1 = {0, 0, 0, 0};
    if (s0 < s1)     lb0 = *(const uint4*)(XLR + (size_t)srcPos[s0] * D2 + lane * 8);
    if (s0 + 1 < s1) lb1 = *(const uint4*)(XLR + (size_t)srcPos[s0 + 1] * D2 + lane * 8);

    for (int i = s0; i < s1; ++i) {
        uint4 cur = lb0;
        lb0 = lb1;
        if (i + 2 < s1)
            lb1 = *(const uint4*)(XLR + (size_t)srcPos[i + 2] * D2 + lane * 8);

        float xl[8]; unpack8(cur, xl);
        float sa = 0.f, sb = 0.f;
        #pragma unroll
        for (int j = 0; j < 4; ++j) {
            float t = xl[j] + xr[j];
            t = fmaxf(t, 0.2f * t);          // leaky relu (valid both signs)
            sa = fmaf(t, at[j], sa);
        }
        #pragma unroll
        for (int j = 4; j < 8; ++j) {
            float t = xl[j] + xr[j];
            t = fmaxf(t, 0.2f * t);
            sb = fmaf(t, at[j], sb);
        }
        float s = sa + sb;
        s += __shfl_xor(s, 1);
        s += __shfl_xor(s, 2);
        s += __shfl_xor(s, 4);
        s += __shfl_xor(s, 8);               // 16 lanes of head hold logit
        s = fminf(fmaxf(s, -60.f), 60.f);    // shift-free softmax, clamped
        float p = __expf(s);
        den += p;
        #pragma unroll
        for (int j = 0; j < 8; ++j) acc[j] = fmaf(p, xl[j], acc[j]);
    }
    float r = 1.f / den;

    const float4* b4 = (const float4*)(bias + lane * 8);
    float4 ba = b4[0], bb = b4[1];
    float bi[8] = {ba.x, ba.y, ba.z, ba.w, bb.x, bb.y, bb.z, bb.w};
    uint4 ou;
    unsigned* ow = (unsigned*)&ou;
    #pragma unroll
    for (int j = 0; j < 4; ++j) {
        float o0 = acc[2 * j] * r + bi[2 * j];
        float o1 = acc[2 * j + 1] * r + bi[2 * j + 1];
        o0 = o0 > 0.f ? o0 : (__expf(o0) - 1.f);   // ELU
        o1 = o1 > 0.f ? o1 : (__expf(o1) - 1.f);
        __hip_bfloat162 h{__float2bfloat16(o0), __float2bfloat16(o1)};
        ow[j] = *(unsigned*)&h;
    }
    *(uint4*)(Hout + (size_t)v * D + lane * 8) = ou;
}

// ---------------------------------------------------------------------------
extern "C" void kernel_launch(void* const* d_in, const int* in_sizes, int n_in,
                              void* d_out, int out_size, void* d_ws, size_t ws_size,
                              hipStream_t stream) {
    const float* x    = (const float*)d_in[0];
    const int*   ei   = (const int*)d_in[1];
    const float* W1l  = (const float*)d_in[2];
    const float* W1r  = (const float*)d_in[3];
    const float* att1 = (const float*)d_in[4];
    const float* b1   = (const float*)d_in[5];
    const float* W2l  = (const float*)d_in[6];
    const float* W2r  = (const float*)d_in[7];
    const float* att2 = (const float*)d_in[8];
    const float* b2   = (const float*)d_in[9];
    const float* Wc   = (const float*)d_in[10];
    const float* bc   = (const float*)d_in[11];
    float* out = (float*)d_out;

    const int* srcIdx = ei;
    const int* dstIdx = ei + EE;

    constexpr int NB = (NN + 1023) / 1024;   // 49 scan blocks

    // workspace carve — total ≈ 166 MB
    bf16* XLR  = (bf16*)d_ws;                    // NN*D2   (XL || XR)
    bf16* Hb   = XLR + (size_t)NN * D2;          // NN*D
    bf16* Xpad = Hb + (size_t)NN * D;            // NN*F0P
    bf16* W2T  = Xpad + (size_t)NN * F0P;        // 1024*D   (W2lT || W2rT rows)
    bf16* W1T  = W2T + (size_t)D2 * D;           // 1024*F0P
    bf16* WcT  = W1T + (size_t)D2 * F0P;         // 128*D
    int* cnt   = (int*)(WcT + (size_t)128 * D);  // NN
    int* cnt2  = cnt + NN;                       // NN
    int* off   = cnt2 + NN;                      // NN+1
    int* srcPos= off + (NN + 1);                 // EP
    int* bsum  = srcPos + EP;                    // NB
    int* bbase = bsum + NB;                      // NB

    // ---- one-time per call: CSR build + weight prep ----
    zero_ints<<<(2 * NN + 255) / 256, 256, 0, stream>>>(cnt, 2 * NN);
    count_dst<<<(EP + 255) / 256, 256, 0, stream>>>(dstIdx, cnt);
    scan_blocks<<<NB, 1024, 0, stream>>>(cnt, off, bsum);
    scan_bsums<<<1, 64, 0, stream>>>(bsum, bbase, off, NB);
    add_base<<<NB, 1024, 0, stream>>>(off, bbase);
    fill_srcpos<<<(EP + 255) / 256, 256, 0, stream>>>(srcIdx, dstIdx, off, cnt2, srcPos);

    dim3 ctGrid(D / 32, D / 32, 2);
    convert_transpose2<<<ctGrid, 256, 0, stream>>>(W2l, W2r, W2T);
    dim3 w1Grid(D, 2);
    conv_transpose_w1<<<w1Grid, F0P, 0, stream>>>(W1l, W1r, W1T);
    conv_transpose_wc<<<128, 256, 0, stream>>>(Wc, WcT);
    pad_convert_x<<<(NN * F0P + 255) / 256, 256, 0, stream>>>(x, Xpad);

    // fused L+R GEMM: N=1024, grid.y padded so the XCD swizzle covers all slabs
    dim3 gemmGrid(D2 / 128, ((NN + 127) / 128 + 7) / 8 * 8 + 8);  // 8 x 400
    int nodeBlocks = (NN + 3) / 4;

    // ---- layer 1 (Xpad bf16, K=64): one GEMM produces XL||XR ----
    gemm_mfma_bt<bf16><<<gemmGrid, 256, 0, stream>>>(Xpad, W1T, XLR, nullptr, NN, D2, F0P);
    gat_edge_fused<<<nodeBlocks, 256, 0, stream>>>(XLR, att1, off, srcPos, b1, Hb);

    // ---- layers 2 & 3 (bf16 Hb, K=512; conv2 applied twice) ----
    for (int rep = 0; rep < 2; ++rep) {
        gemm_mfma_bt<bf16><<<gemmGrid, 256, 0, stream>>>(Hb, W2T, XLR, nullptr, NN, D2, D);
        gat_edge_fused<<<nodeBlocks, 256, 0, stream>>>(XLR, att2, off, srcPos, b2, Hb);
    }

    // ---- classifier: C[NN,49] fp32 = Hb @ Wc + bc (N padded to 128) ----
    dim3 gridc(1, (NN + 127) / 128);
    gemm_mfma_bt<float><<<gridc, 256, 0, stream>>>(Hb, WcT, out, bc, NN, OUTC, D);
}